// Round 10
// baseline (272.276 us; speedup 1.0000x reference)
//
#include <hip/hip_runtime.h>
#include <hip/hip_bf16.h>
#include <cstdint>
#include <cstddef>

typedef __attribute__((ext_vector_type(8))) short bf16x8;
typedef __attribute__((ext_vector_type(4))) short bf16x4;
typedef __attribute__((ext_vector_type(4))) float f32x4;
typedef __attribute__((ext_vector_type(4))) unsigned short u16x4;
typedef unsigned short u16;
typedef unsigned int u32;

__device__ __forceinline__ float bf2f(u16 v) {
    union { u32 u; float f; } c; c.u = ((u32)v) << 16; return c.f;
}
__device__ __forceinline__ u16 f2bf(float f) {
    union { float f; u32 u; } c; c.f = f;
    u32 u = c.u;
    return (u16)((u + 0x7FFFu + ((u >> 16) & 1u)) >> 16);  // RNE
}

#define MFMA16(a, b, c) __builtin_amdgcn_mfma_f32_16x16x32_bf16((a), (b), (c), 0, 0, 0)

#if __has_builtin(__builtin_amdgcn_mfma_f32_16x16x16bf16_1k)
#define MFMA1K(a, b, c) __builtin_amdgcn_mfma_f32_16x16x16bf16_1k((a), (b), (c), 0, 0, 0)
#define MFMA1K_ASM 0
#else
__device__ __forceinline__ f32x4 mfma1k_asm(bf16x4 a, bf16x4 b, f32x4 c) {
    asm volatile("v_mfma_f32_16x16x16_bf16 %0, %1, %2, %0" : "+v"(c) : "v"(a), "v"(b));
    return c;
}
#define MFMA1K(a, b, c) mfma1k_asm((a), (b), (c))
#define MFMA1K_ASM 1
#endif

#if __has_builtin(__builtin_amdgcn_exp2f)
#define EXP2F(x) __builtin_amdgcn_exp2f(x)
#else
#define EXP2F(x) exp2f(x)
#endif

#if __has_builtin(__builtin_amdgcn_global_load_lds)
#define HAVE_GLL 1
__device__ __forceinline__ void gload16(const u16* g, u16* l, int lane) {
    (void)lane;
    __builtin_amdgcn_global_load_lds((__attribute__((address_space(1))) void*)(void*)g,
                                     (__attribute__((address_space(3))) void*)l, 16, 0, 0);
}
#else
#define HAVE_GLL 0
__device__ __forceinline__ void gload16(const u16* g, u16* l, int lane) {
    *(uint4*)(l + lane * 8) = *(const uint4*)g;
}
#endif

union U8 { u16 h[8]; uint4 v; };

__device__ __forceinline__ U8 cvt8(float4 a, float4 b) {
    U8 u;
    u.h[0] = f2bf(a.x); u.h[1] = f2bf(a.y); u.h[2] = f2bf(a.z); u.h[3] = f2bf(a.w);
    u.h[4] = f2bf(b.x); u.h[5] = f2bf(b.y); u.h[6] = f2bf(b.z); u.h[7] = f2bf(b.w);
    return u;
}

// ---------------------------------------------------------------------------
// W transpose+cvt: Wt[n][k] bf16 = W[k][n] fp32.  64x64 LDS tiles.
// ---------------------------------------------------------------------------
struct TArgs { const float* src[4]; u16* dst[4]; };

__global__ __launch_bounds__(256)
void transpose_kernel(TArgs ta)
{
    __shared__ float T[64][65];
    const float* W = ta.src[blockIdx.z];
    u16* Wt = ta.dst[blockIdx.z];
    const int tid = threadIdx.x;
    const int bx = blockIdx.x, by = blockIdx.y;
    const int rr = tid >> 4, c4 = (tid & 15) * 4;
#pragma unroll
    for (int i = 0; i < 4; ++i) {
        int r = rr + i * 16;
        float4 v = *(const float4*)(W + (size_t)(by * 64 + r) * 1024 + bx * 64 + c4);
        T[r][c4] = v.x; T[r][c4 + 1] = v.y; T[r][c4 + 2] = v.z; T[r][c4 + 3] = v.w;
    }
    __syncthreads();
#pragma unroll
    for (int i = 0; i < 4; ++i) {
        int n = rr + i * 16;
        u16 o0 = f2bf(T[c4][n]), o1 = f2bf(T[c4 + 1][n]);
        u16 o2 = f2bf(T[c4 + 2][n]), o3 = f2bf(T[c4 + 3][n]);
        uint2 pk;
        pk.x = (u32)o0 | ((u32)o1 << 16);
        pk.y = (u32)o2 | ((u32)o3 << 16);
        *(uint2*)(Wt + (size_t)(bx * 64 + n) * 1024 + by * 64 + c4) = pk;
    }
}

// ---------------------------------------------------------------------------
// fp32 -> bf16 bulk convert (8 elems/thread)
// ---------------------------------------------------------------------------
__global__ __launch_bounds__(256)
void cvt_bf16_kernel(const float* __restrict__ src, u16* __restrict__ dst)
{
    const size_t i = ((size_t)blockIdx.x * 256 + threadIdx.x) * 8;
    float4 a = *(const float4*)(src + i);
    float4 b = *(const float4*)(src + i + 4);
    *(uint4*)(dst + i) = cvt8(a, b).v;
}

// ---------------------------------------------------------------------------
// GEMM args (z-fused outputs)
// ---------------------------------------------------------------------------
struct GArgs {
    const u16* Bt[3];
    const float* bias[3];
    void* out[3];
    int mode[3];
};

// ---------------------------------------------------------------------------
// 128x64-tile NT GEMM, K=1024, BK=64.  A bf16 [M][1024]; Bt bf16 rows=outcols.
// Staging via global_load_lds (16B, linear LDS) with XOR-swizzled source cols;
// reads deswizzle => conflict-free ds_read_b128.  4 waves, each 32x64 out.
// LDS 24 KB.  mode 0: bf16 row-major; 1: bf16 [col][M]; 2: fp32 + resid.
// ---------------------------------------------------------------------------
__global__ __launch_bounds__(256, 2)
void gemm128_kernel(const u16* __restrict__ A, GArgs ga, const float* __restrict__ resid,
                    int M, int bcol0, int Nout)
{
    const int z = blockIdx.z;
    const u16* Bt = ga.Bt[z];
    const float* bias = ga.bias[z];
    void* Cout = ga.out[z];
    const int mode = ga.mode[z];

    __shared__ __align__(1024) u16 As[128 * 64];
    __shared__ __align__(1024) u16 Bs[64 * 64];
    const int tid = threadIdx.x;
    const int bm = blockIdx.y * 128, bn = blockIdx.x * 64;
    const int wave = tid >> 6, lane = tid & 63;
    const int quad = lane >> 4, l16 = lane & 15;
    const int wr = wave * 32;
    const int srow = lane >> 3;                 // 0..7
    const int scol = ((lane & 7) ^ srow) * 8;   // swizzled source col (u16)

    const u16* Ab = A + (size_t)(bm + srow) * 1024 + scol;
    const u16* Bb = Bt + (size_t)(bcol0 + bn + srow) * 1024 + scol;

    f32x4 acc[2][4] = {};

    for (int k0 = 0; k0 < 1024; k0 += 64) {
        __syncthreads();   // prior iteration's LDS reads complete
#pragma unroll
        for (int i = 0; i < 4; ++i)
            gload16(Ab + (size_t)(wave * 32 + i * 8) * 1024 + k0,
                    As + (wave * 32 + i * 8) * 64, lane);
#pragma unroll
        for (int i = 0; i < 2; ++i)
            gload16(Bb + (size_t)(wave * 16 + i * 8) * 1024 + k0,
                    Bs + (wave * 16 + i * 8) * 64, lane);
        __syncthreads();   // compiler drains vmcnt before barrier -> data landed
#pragma unroll
        for (int kh = 0; kh < 2; ++kh) {
            const int chunk = ((kh * 4 + quad) ^ (l16 & 7)) * 8;   // deswizzle
            bf16x8 af[2], bf[4];
#pragma unroll
            for (int mi = 0; mi < 2; ++mi)
                af[mi] = *(const bf16x8*)(As + (wr + mi * 16 + l16) * 64 + chunk);
#pragma unroll
            for (int ni = 0; ni < 4; ++ni)
                bf[ni] = *(const bf16x8*)(Bs + (ni * 16 + l16) * 64 + chunk);
#pragma unroll
            for (int mi = 0; mi < 2; ++mi)
#pragma unroll
                for (int ni = 0; ni < 4; ++ni)
                    acc[mi][ni] = MFMA16(af[mi], bf[ni], acc[mi][ni]);
        }
    }

#pragma unroll
    for (int mi = 0; mi < 2; ++mi)
#pragma unroll
        for (int ni = 0; ni < 4; ++ni) {
            int col = bn + ni * 16 + l16;
            float bb = bias[bcol0 + col];
#pragma unroll
            for (int r = 0; r < 4; ++r) {
                int row = bm + wr + mi * 16 + quad * 4 + r;
                float v = acc[mi][ni][r] + bb;
                if (mode == 0) {
                    ((u16*)Cout)[(size_t)row * Nout + col] = f2bf(v);
                } else if (mode == 1) {
                    ((u16*)Cout)[(size_t)col * M + row] = f2bf(v);
                } else {
                    size_t idx = (size_t)row * Nout + col;
                    ((float*)Cout)[idx] = v + resid[idx];
                }
            }
        }
}

// ---------------------------------------------------------------------------
// 64x64 NT GEMM (fallback path)
// ---------------------------------------------------------------------------
__global__ __launch_bounds__(256, 4)
void gemm_nt_kernel(const void* __restrict__ Av, int abf, GArgs ga,
                    const float* __restrict__ resid, int M, int K,
                    int bcol0, int Nout)
{
    const int z = blockIdx.z;
    const u16* Bt = ga.Bt[z];
    const float* bias = ga.bias[z];
    void* Cout = ga.out[z];
    const int mode = ga.mode[z];

    __shared__ __align__(16) u16 As[64 * 72];
    __shared__ __align__(16) u16 Bs[64 * 72];
    const int tid = threadIdx.x;
    const int bm = blockIdx.y * 64, bn = blockIdx.x * 64;
    const int wave = tid >> 6, lane = tid & 63;
    const int quad = lane >> 4, l16 = lane & 15;
    const int wm = (wave >> 1) * 32, wn = (wave & 1) * 32;
    const int ar = tid >> 2, ac = (tid & 3) * 16;

    f32x4 acc[2][2] = {};

    for (int k0 = 0; k0 < K; k0 += 64) {
        uint4 a0v, a1v;
        if (abf) {
            const u16* A16 = (const u16*)Av + (size_t)(bm + ar) * K + k0 + ac;
            a0v = *(const uint4*)A16;
            a1v = *(const uint4*)(A16 + 8);
        } else {
            const float* ap = (const float*)Av + (size_t)(bm + ar) * K + k0 + ac;
            a0v = cvt8(*(const float4*)ap, *(const float4*)(ap + 4)).v;
            a1v = cvt8(*(const float4*)(ap + 8), *(const float4*)(ap + 12)).v;
        }
        const u16* btp = Bt + (size_t)(bcol0 + bn + ar) * K + k0 + ac;
        uint4 b0v = *(const uint4*)btp;
        uint4 b1v = *(const uint4*)(btp + 8);
        __syncthreads();
        *(uint4*)(As + ar * 72 + ac) = a0v;
        *(uint4*)(As + ar * 72 + ac + 8) = a1v;
        *(uint4*)(Bs + ar * 72 + ac) = b0v;
        *(uint4*)(Bs + ar * 72 + ac + 8) = b1v;
        __syncthreads();
#pragma unroll
        for (int kh = 0; kh < 64; kh += 32) {
            bf16x8 a0 = *(const bf16x8*)(As + (wm + l16) * 72 + kh + quad * 8);
            bf16x8 a1 = *(const bf16x8*)(As + (wm + 16 + l16) * 72 + kh + quad * 8);
            bf16x8 b0 = *(const bf16x8*)(Bs + (wn + l16) * 72 + kh + quad * 8);
            bf16x8 b1 = *(const bf16x8*)(Bs + (wn + 16 + l16) * 72 + kh + quad * 8);
            acc[0][0] = MFMA16(a0, b0, acc[0][0]);
            acc[0][1] = MFMA16(a0, b1, acc[0][1]);
            acc[1][0] = MFMA16(a1, b0, acc[1][0]);
            acc[1][1] = MFMA16(a1, b1, acc[1][1]);
        }
    }

#pragma unroll
    for (int i = 0; i < 2; ++i) {
#pragma unroll
        for (int j = 0; j < 2; ++j) {
            int col = bn + wn + j * 16 + l16;
            float bb = bias[bcol0 + col];
#pragma unroll
            for (int r = 0; r < 4; ++r) {
                int row = bm + wm + i * 16 + quad * 4 + r;
                float v = acc[i][j][r] + bb;
                if (mode == 0) {
                    ((u16*)Cout)[(size_t)row * Nout + col] = f2bf(v);
                } else if (mode == 1) {
                    ((u16*)Cout)[(size_t)col * M + row] = f2bf(v);
                } else {
                    ((float*)Cout)[(size_t)row * Nout + col] = v + resid[(size_t)row * Nout + col];
                }
            }
        }
    }
}

// ---------------------------------------------------------------------------
// Far-tile constants: cst[(hg*4+w)*2048+s]
// ---------------------------------------------------------------------------
__global__ __launch_bounds__(256)
void consts_kernel(const u16* __restrict__ Qg, const u16* __restrict__ Kg,
                   const u16* __restrict__ posKg, const u16* __restrict__ posQg,
                   float* __restrict__ cst, int ld)
{
    const int s = blockIdx.x * 256 + threadIdx.x;
    const int hg = blockIdx.y;
    float d0 = 0.f, d1 = 0.f, d2 = 0.f, d3 = 0.f;
#pragma unroll
    for (int c = 0; c < 64; c += 8) {
        U8 q, k, p0, p1, r0, r1;
        q.v  = *(const uint4*)(Qg + (size_t)s * ld + hg * 64 + c);
        k.v  = *(const uint4*)(Kg + (size_t)s * ld + hg * 64 + c);
        p0.v = *(const uint4*)(posKg + (size_t)0 * ld + hg * 64 + c);
        p1.v = *(const uint4*)(posKg + (size_t)1023 * ld + hg * 64 + c);
        r0.v = *(const uint4*)(posQg + (size_t)0 * ld + hg * 64 + c);
        r1.v = *(const uint4*)(posQg + (size_t)1023 * ld + hg * 64 + c);
#pragma unroll
        for (int j = 0; j < 8; ++j) {
            float qq = bf2f(q.h[j]), kk = bf2f(k.h[j]);
            d0 += qq * bf2f(p0.h[j]);
            d1 += qq * bf2f(p1.h[j]);
            d2 += kk * bf2f(r0.h[j]);
            d3 += kk * bf2f(r1.h[j]);
        }
    }
    cst[(size_t)(hg * 4 + 0) * 2048 + s] = d0;
    cst[(size_t)(hg * 4 + 1) * 2048 + s] = d1;
    cst[(size_t)(hg * 4 + 2) * 2048 + s] = d2;
    cst[(size_t)(hg * 4 + 3) * 2048 + s] = d3;
}

// ---------------------------------------------------------------------------
// Fused flash attention (r9 verified version -- 91 us, untouched).
// ---------------------------------------------------------------------------
__global__ __launch_bounds__(256, 2)
void attn_kernel(const u16* __restrict__ Qg, const u16* __restrict__ Kg,
                 const u16* __restrict__ Vtg, const u16* __restrict__ posKg,
                 const u16* __restrict__ posQg, const float* __restrict__ cst,
                 u16* __restrict__ ctx, int h0, int ld)
{
    __shared__ __align__(16) u16 Ks[64 * 72];
    __shared__ __align__(16) u16 Vs[64 * 72];
    __shared__ __align__(16) u16 pKs[128 * 72];
    __shared__ __align__(16) u16 pQs[128 * 72];
    __shared__ __align__(16) u16 bandC[4 * 16 * 72];
    __shared__ __align__(16) u16 bandP[16 * 264];
    const int tid = threadIdx.x;

    int hg, qi;
    if (gridDim.y == 16) {
        const int b = blockIdx.x + (blockIdx.y << 5);
        const int xcd = b & 7, r = b >> 3;
        hg = (xcd << 1) | (r & 1);
        qi = r >> 1;
    } else {
        hg = blockIdx.y; qi = blockIdx.x;
    }
    const int q0 = qi * 64;
    const int wave = tid >> 6, lane = tid & 63, quad = lane >> 4, l16 = lane & 15;
    const float CSC = 0.07216878364870322f * 1.44269504f;

    bf16x8 aq0 = *(const bf16x8*)(Qg + (q0 + wave * 16 + l16) * ld + hg * 64 + quad * 8);
    bf16x8 aq1 = *(const bf16x8*)(Qg + (q0 + wave * 16 + l16) * ld + hg * 64 + 32 + quad * 8);

    float cq0s = 0.f, cq1s = 0.f;
    if (cst) {
        int qgl = q0 + wave * 16 + l16;
        cq0s = cst[(hg * 4 + 0) * 2048 + qgl];
        cq1s = cst[(hg * 4 + 1) * 2048 + qgl];
    }

    const int sm0 = tid >> 3, sd0 = (tid & 7) * 8;
    const int sm1 = sm0 + 32;

    auto isfar = [&](int kt) {
        const int d = kt - q0;
        return cst && (d >= 576 || d <= -576);
    };

    auto stage = [&](int kt, bool withpos) {
        const u16* kgb = Kg + hg * 64 + sd0;
        const u16* vgb = Vtg + kt + sd0;
        uint4 k0 = *(const uint4*)(kgb + (kt + sm0) * ld);
        uint4 k1 = *(const uint4*)(kgb + (kt + sm1) * ld);
        uint4 v0 = *(const uint4*)(vgb + (hg * 64 + sm0) * 2048);
        uint4 v1 = *(const uint4*)(vgb + (hg * 64 + sm1) * 2048);
        if (withpos) {
            const int kap = q0 - kt + 449;
            int r0 = kap + sm0;      r0 = r0 < 0 ? 0 : (r0 > 1023 ? 1023 : r0);
            int r1 = kap + sm0 + 32; r1 = r1 < 0 ? 0 : (r1 > 1023 ? 1023 : r1);
            int r2 = kap + sm0 + 64; r2 = r2 < 0 ? 0 : (r2 > 1023 ? 1023 : r2);
            int r3 = kap + sm0 + 96; r3 = r3 < 0 ? 0 : (r3 > 1023 ? 1023 : r3);
            const u16* pKb = posKg + hg * 64 + sd0;
            const u16* pQb = posQg + hg * 64 + sd0;
            uint4 a0 = *(const uint4*)(pKb + r0 * ld);
            uint4 a1 = *(const uint4*)(pKb + r1 * ld);
            uint4 a2 = *(const uint4*)(pKb + r2 * ld);
            uint4 a3 = *(const uint4*)(pKb + r3 * ld);
            uint4 b0 = *(const uint4*)(pQb + r0 * ld);
            uint4 b1 = *(const uint4*)(pQb + r1 * ld);
            uint4 b2 = *(const uint4*)(pQb + r2 * ld);
            uint4 b3 = *(const uint4*)(pQb + r3 * ld);
            *(uint4*)(Ks + sm0 * 72 + sd0) = k0;
            *(uint4*)(Ks + sm1 * 72 + sd0) = k1;
            *(uint4*)(Vs + sm0 * 72 + sd0) = v0;
            *(uint4*)(Vs + sm1 * 72 + sd0) = v1;
            *(uint4*)(pKs + sm0 * 72 + sd0) = a0;
            *(uint4*)(pKs + (sm0 + 32) * 72 + sd0) = a1;
            *(uint4*)(pKs + (sm0 + 64) * 72 + sd0) = a2;
            *(uint4*)(pKs + (sm0 + 96) * 72 + sd0) = a3;
            *(uint4*)(pQs + sm0 * 72 + sd0) = b0;
            *(uint4*)(pQs + (sm0 + 32) * 72 + sd0) = b1;
            *(uint4*)(pQs + (sm0 + 64) * 72 + sd0) = b2;
            *(uint4*)(pQs + (sm0 + 96) * 72 + sd0) = b3;
        } else {
            *(uint4*)(Ks + sm0 * 72 + sd0) = k0;
            *(uint4*)(Ks + sm1 * 72 + sd0) = k1;
            *(uint4*)(Vs + sm0 * 72 + sd0) = v0;
            *(uint4*)(Vs + sm1 * 72 + sd0) = v1;
        }
    };

    auto bandcomp = [&]() {
        bf16x8 aP0 = *(const bf16x8*)(Ks + (wave * 16 + l16) * 72 + quad * 8);
        bf16x8 aP1 = *(const bf16x8*)(Ks + (wave * 16 + l16) * 72 + 32 + quad * 8);
        const int iC0 = wave * 16 + l16;
        const int iP0 = 48 - wave * 16 + l16;
        u16* bC = bandC + wave * 1152;
        u16* bP = bandP;
#pragma unroll
        for (int n = 0; n < 5; ++n) {
            const u16* pK = pKs + (iC0 + n * 16) * 72;
            const u16* pQ = pQs + (iP0 + n * 16) * 72;
            bf16x8 bK0 = *(const bf16x8*)(pK + quad * 8);
            bf16x8 bK1 = *(const bf16x8*)(pK + 32 + quad * 8);
            bf16x8 bQ0 = *(const bf16x8*)(pQ + quad * 8);
            bf16x8 bQ1 = *(const bf16x8*)(pQ + 32 + quad * 8);
            f32x4 aC = {0.f, 0.f, 0.f, 0.f}, aP = {0.f, 0.f, 0.f, 0.f};
            aC = MFMA16(aq0, bK0, aC);
            aC = MFMA16(aq1, bK1, aC);
            aP = MFMA16(aP0, bQ0, aP);
            aP = MFMA16(aP1, bQ1, aP);
#pragma unroll
            for (int r = 0; r < 4; ++r) {
                int q15 = quad * 4 + r;
                int k = q15 + 63 - n * 16 - l16;
                if ((unsigned)k < 64u) bC[q15 * 72 + k] = f2bf(aC[r]);
                int qs = n * 16 + l16 + quad * 4 + r - 15;
                if ((unsigned)qs < 64u) bP[(wave * 4 + quad) * 264 + qs * 4 + r] = f2bf(aP[r]);
            }
        }
    };

    stage(0, !isfar(0));
    __syncthreads();

    f32x4 OTa[4] = {}, OTb[4] = {};
    float lr4[4] = {0.f, 0.f, 0.f, 0.f};

    for (int kt = 0; kt < 2048; kt += 64) {
        const int diff = kt - q0;
        const bool far = cst && (diff >= 576 || diff <= -576);
        const bool havenext = (kt + 64 < 2048);
        const bool nextnear = havenext && !isfar(kt + 64);

        f32x4 sT[4];
#pragma unroll
        for (int j = 0; j < 4; ++j) {
            f32x4 z = {0.f, 0.f, 0.f, 0.f};
            bf16x8 a0 = *(const bf16x8*)(Ks + (j * 16 + l16) * 72 + quad * 8);
            bf16x8 a1 = *(const bf16x8*)(Ks + (j * 16 + l16) * 72 + 32 + quad * 8);
            z = MFMA16(a0, aq0, z);
            z = MFMA16(a1, aq1, z);
            sT[j] = z;
        }

        if (!far) {
            bandcomp();
            __syncthreads();
        }

        bf16x4 pb[4];
        if (far) {
            const float cqs = (diff > 0) ? cq0s : cq1s;
            const float* pc = cst + (hg * 4 + (diff > 0 ? 2 : 3)) * 2048 + kt;
#pragma unroll
            for (int j = 0; j < 4; ++j) {
                float4 ck4 = *(const float4*)(pc + j * 16 + quad * 4);
                const float* ck = (const float*)&ck4;
#pragma unroll
                for (int r = 0; r < 4; ++r) {
                    float t = sT[j][r] + cqs + ck[r];
                    float e = EXP2F(fminf(t * CSC, 86.5f));
                    lr4[j] += e;
                    pb[j][r] = (short)f2bf(e);
                }
            }
        } else {
            const u16* bC = bandC + wave * 1152 + l16 * 72;
            const u16* bP = bandP + (wave * 16 + l16) * 4;
#pragma unroll
            for (int j = 0; j < 4; ++j) {
                u16x4 c4 = *(const u16x4*)(bC + j * 16 + quad * 4);
                u16x4 p4 = *(const u16x4*)(bP + (j * 4 + quad) * 264);
#pragma unroll
                for (int r = 0; r < 4; ++r) {
                    float t = sT[j][r] + bf2f(c4[r]) + bf2f(p4[r]);
                    float e = EXP2F(fminf(t * CSC, 86.5f));
                    lr4[j] += e;
                    pb[j][r] = (short)f2bf(e);
                }
            }
        }

#pragma unroll
        for (int jd = 0; jd < 4; ++jd) {
            const u16* vrow = Vs + (jd * 16 + l16) * 72;
            OTa[jd] = MFMA1K(*(const bf16x4*)(vrow + quad * 4), pb[0], OTa[jd]);
            OTb[jd] = MFMA1K(*(const bf16x4*)(vrow + 16 + quad * 4), pb[1], OTb[jd]);
            OTa[jd] = MFMA1K(*(const bf16x4*)(vrow + 32 + quad * 4), pb[2], OTa[jd]);
            OTb[jd] = MFMA1K(*(const bf16x4*)(vrow + 48 + quad * 4), pb[3], OTb[jd]);
        }

        __syncthreads();
        if (havenext) {
            stage(kt + 64, nextnear);
            __syncthreads();
        }
    }

#if MFMA1K_ASM
    asm volatile("s_nop 7\n\ts_nop 7" ::);
#endif

    float lr = (lr4[0] + lr4[1]) + (lr4[2] + lr4[3]);
    lr += __shfl_xor(lr, 16, 64);
    lr += __shfl_xor(lr, 32, 64);
    float inv = 1.0f / fmaxf(lr, 1e-20f);
    const int row = q0 + wave * 16 + l16;
#pragma unroll
    for (int jd = 0; jd < 4; ++jd) {
        u16x4 o;
#pragma unroll
        for (int r = 0; r < 4; ++r) o[r] = f2bf((OTa[jd][r] + OTb[jd][r]) * inv);
        *(u16x4*)(ctx + row * 1024 + (h0 + hg) * 64 + jd * 16 + quad * 4) = o;
    }
}

// ---------------------------------------------------------------------------
// Row LayerNorm: x (fp32, ws) -> d_out (fp32)
// ---------------------------------------------------------------------------
__global__ __launch_bounds__(256, 4)
void ln_kernel(const float* __restrict__ x, const float* __restrict__ g,
               const float* __restrict__ b, float* __restrict__ out)
{
    const int row = blockIdx.x;
    const int tid = threadIdx.x;
    const int wave = tid >> 6, lane = tid & 63;
    const float* xr = x + (size_t)row * 1024;
    float v[4]; float s = 0.f;
#pragma unroll
    for (int i = 0; i < 4; ++i) { v[i] = xr[tid + i * 256]; s += v[i]; }
    __shared__ float red[4];
    __shared__ float red2[4];
#pragma unroll
    for (int m = 1; m < 64; m <<= 1) s += __shfl_xor(s, m, 64);
    if (lane == 0) red[wave] = s;
    __syncthreads();
    float mu = (red[0] + red[1] + red[2] + red[3]) * (1.f / 1024.f);
    float vs = 0.f;
#pragma unroll
    for (int i = 0; i < 4; ++i) { float d = v[i] - mu; vs += d * d; }
#pragma unroll
    for (int m = 1; m < 64; m <<= 1) vs += __shfl_xor(vs, m, 64);
    if (lane == 0) red2[wave] = vs;
    __syncthreads();
    float var = (red2[0] + red2[1] + red2[2] + red2[3]) * (1.f / 1024.f);
    float rstd = rsqrtf(var + 1e-5f);
#pragma unroll
    for (int i = 0; i < 4; ++i) {
        int c = tid + i * 256;
        out[(size_t)row * 1024 + c] = (v[i] - mu) * rstd * g[c] + b[c];
    }
}

// ---------------------------------------------------------------------------
extern "C" void kernel_launch(void* const* d_in, const int* in_sizes, int n_in,
                              void* d_out, int out_size, void* d_ws, size_t ws_size,
                              hipStream_t stream)
{
    const float* hs  = (const float*)d_in[0];
    const float* rel = (const float*)d_in[2];
    const float* Wq  = (const float*)d_in[3];
    const float* bq  = (const float*)d_in[4];
    const float* Wk  = (const float*)d_in[5];
    const float* bk  = (const float*)d_in[6];
    const float* Wv  = (const float*)d_in[7];
    const float* bv  = (const float*)d_in[8];
    const float* Wo  = (const float*)d_in[9];
    const float* bo  = (const float*)d_in[10];
    const float* lng = (const float*)d_in[11];
    const float* lnb = (const float*)d_in[12];

    u16* Wqt = (u16*)d_out;
    u16* Wkt = Wqt + (size_t)1024 * 1024;
    u16* Wvt = Wkt + (size_t)1024 * 1024;
    u16* Wot = Wvt + (size_t)1024 * 1024;
    float* cst = (float*)d_out;          // 16*4*2048 floats = 512 KB

    const size_t MB = 1024 * 1024;
    size_t fixed = 256 + 4 * MB + 4096;
    int G = 1;
    if (ws_size > fixed + MB) {
        size_t g = (ws_size - fixed) / MB;
        G = g > 16 ? 16 : (int)g;
    }
    if (G < 1) G = 1;

    char* w = (char*)d_ws;
    size_t off = 0;
    auto take = [&](size_t n) { void* p = w + off; off = (off + n + 255) & ~(size_t)255; return p; };
    (void)take(256);
    u16* ctx = (u16*)take((size_t)2048 * 1024 * 2);
    float* xalt = nullptr;
    if (G < 8) {
        size_t budget = (ws_size > fixed + 8 * MB) ? (ws_size - fixed - 8 * MB) / MB : 1;
        G = budget < 1 ? 1 : (budget > 16 ? 16 : (int)budget);
        xalt = (float*)take((size_t)2048 * 1024 * 4);
    }
    u16* Qg    = (u16*)take((size_t)2048 * 64 * G * 2);
    u16* Kg    = (u16*)take((size_t)2048 * 64 * G * 2);
    u16* Vtg   = (u16*)take((size_t)64 * G * 2048 * 2);
    u16* posKg = (u16*)take((size_t)1024 * 64 * G * 2);
    u16* posQg = (u16*)take((size_t)1024 * 64 * G * 2);
    float* x = xalt ? xalt : (float*)Qg;

    const bool full = (G == 16);

    // bf16 copies of hs/rel for the fast GEMM path (needs ws room)
    u16* hsb = nullptr; u16* relb = nullptr;
    if (full && HAVE_GLL) {
        size_t need = (size_t)2048 * 1024 * 2 + (size_t)1024 * 1024 * 2 + 1024;
        if (off + need <= ws_size) {
            hsb  = (u16*)take((size_t)2048 * 1024 * 2);
            relb = (u16*)take((size_t)1024 * 1024 * 2);
        }
    }
    const bool fastg = (hsb != nullptr);

    dim3 blk(256);

    TArgs ta;
    ta.src[0] = Wq; ta.src[1] = Wk; ta.src[2] = Wv; ta.src[3] = Wo;
    ta.dst[0] = Wqt; ta.dst[1] = Wkt; ta.dst[2] = Wvt; ta.dst[3] = Wot;
    transpose_kernel<<<dim3(16, 16, 4), blk, 0, stream>>>(ta);

    if (fastg) {
        cvt_bf16_kernel<<<dim3(1024), blk, 0, stream>>>(hs, hsb);
        cvt_bf16_kernel<<<dim3(512), blk, 0, stream>>>(rel, relb);

        GArgs qa;
        qa.Bt[0] = Wqt; qa.bias[0] = bq; qa.out[0] = Qg;  qa.mode[0] = 0;
        qa.Bt[1] = Wkt; qa.bias[1] = bk; qa.out[1] = Kg;  qa.mode[1] = 0;
        qa.Bt[2] = Wvt; qa.bias[2] = bv; qa.out[2] = Vtg; qa.mode[2] = 1;
        gemm128_kernel<<<dim3(16, 16, 3), blk, 0, stream>>>(hsb, qa, nullptr, 2048, 0, 1024);

        GArgs pa;
        pa.Bt[0] = Wkt; pa.bias[0] = bk; pa.out[0] = posKg; pa.mode[0] = 0;
        pa.Bt[1] = Wqt; pa.bias[1] = bq; pa.out[1] = posQg; pa.mode[1] = 0;
        pa.Bt[2] = Wqt; pa.bias[2] = bq; pa.out[2] = posQg; pa.mode[2] = 0;  // unused z
        gemm128_kernel<<<dim3(16, 8, 2), blk, 0, stream>>>(relb, pa, nullptr, 1024, 0, 1024);

        consts_kernel<<<dim3(8, 16), blk, 0, stream>>>(Qg, Kg, posKg, posQg, cst, 1024);

        attn_kernel<<<dim3(32, 16), blk, 0, stream>>>(Qg, Kg, Vtg, posKg, posQg,
                                                      cst, ctx, 0, 1024);

        GArgs fa;
        fa.Bt[0] = Wot; fa.bias[0] = bo; fa.out[0] = x; fa.mode[0] = 2;
        fa.Bt[1] = Wot; fa.bias[1] = bo; fa.out[1] = x; fa.mode[1] = 2;  // unused z
        fa.Bt[2] = Wot; fa.bias[2] = bo; fa.out[2] = x; fa.mode[2] = 2;  // unused z
        gemm128_kernel<<<dim3(16, 16, 1), blk, 0, stream>>>(ctx, fa, hs, 2048, 0, 1024);
    } else {
        for (int h0 = 0; h0 < 16; h0 += G) {
            int gcnt = (16 - h0) < G ? (16 - h0) : G;
            int Ng = 64 * gcnt, bc0 = 64 * h0;

            GArgs qa;
            qa.Bt[0] = Wqt; qa.bias[0] = bq; qa.out[0] = Qg;  qa.mode[0] = 0;
            qa.Bt[1] = Wkt; qa.bias[1] = bk; qa.out[1] = Kg;  qa.mode[1] = 0;
            qa.Bt[2] = Wvt; qa.bias[2] = bv; qa.out[2] = Vtg; qa.mode[2] = 1;
            gemm_nt_kernel<<<dim3(gcnt, 32, 3), blk, 0, stream>>>(hs, 0, qa, nullptr, 2048, 1024, bc0, Ng);

            GArgs pa;
            pa.Bt[0] = Wkt; pa.bias[0] = bk; pa.out[0] = posKg; pa.mode[0] = 0;
            pa.Bt[1] = Wqt; pa.bias[1] = bq; pa.out[1] = posQg; pa.mode[1] = 0;
            pa.Bt[2] = Wqt; pa.bias[2] = bq; pa.out[2] = posQg; pa.mode[2] = 0;
            gemm_nt_kernel<<<dim3(gcnt, 16, 2), blk, 0, stream>>>(rel, 0, pa, nullptr, 1024, 1024, bc0, Ng);

            if (full)
                consts_kernel<<<dim3(8, G), blk, 0, stream>>>(Qg, Kg, posKg, posQg, cst, Ng);

            attn_kernel<<<dim3(32, gcnt), blk, 0, stream>>>(Qg, Kg, Vtg, posKg, posQg,
                                                            full ? cst : nullptr, ctx, h0, Ng);
        }
        GArgs fa;
        fa.Bt[0] = Wot; fa.bias[0] = bo; fa.out[0] = x; fa.mode[0] = 2;
        fa.Bt[1] = Wot; fa.bias[1] = bo; fa.out[1] = x; fa.mode[1] = 2;
        fa.Bt[2] = Wot; fa.bias[2] = bo; fa.out[2] = x; fa.mode[2] = 2;
        gemm_nt_kernel<<<dim3(16, 32, 1), blk, 0, stream>>>(ctx, 1, fa, hs, 2048, 1024, 0, 1024);
    }

    ln_kernel<<<dim3(2048), blk, 0, stream>>>(x, lng, lnb, (float*)d_out);
}

// Round 12
// 266.524 us; speedup vs baseline: 1.0216x; 1.0216x over previous
//
#include <hip/hip_runtime.h>
#include <hip/hip_bf16.h>
#include <cstdint>
#include <cstddef>

typedef __attribute__((ext_vector_type(8))) short bf16x8;
typedef __attribute__((ext_vector_type(4))) short bf16x4;
typedef __attribute__((ext_vector_type(4))) float f32x4;
typedef __attribute__((ext_vector_type(4))) unsigned short u16x4;
typedef unsigned short u16;
typedef unsigned int u32;

__device__ __forceinline__ float bf2f(u16 v) {
    union { u32 u; float f; } c; c.u = ((u32)v) << 16; return c.f;
}
__device__ __forceinline__ u16 f2bf(float f) {
    union { float f; u32 u; } c; c.f = f;
    u32 u = c.u;
    return (u16)((u + 0x7FFFu + ((u >> 16) & 1u)) >> 16);  // RNE
}

#define MFMA16(a, b, c) __builtin_amdgcn_mfma_f32_16x16x32_bf16((a), (b), (c), 0, 0, 0)

#if __has_builtin(__builtin_amdgcn_mfma_f32_16x16x16bf16_1k)
#define MFMA1K(a, b, c) __builtin_amdgcn_mfma_f32_16x16x16bf16_1k((a), (b), (c), 0, 0, 0)
#define MFMA1K_ASM 0
#else
__device__ __forceinline__ f32x4 mfma1k_asm(bf16x4 a, bf16x4 b, f32x4 c) {
    asm volatile("v_mfma_f32_16x16x16_bf16 %0, %1, %2, %0" : "+v"(c) : "v"(a), "v"(b));
    return c;
}
#define MFMA1K(a, b, c) mfma1k_asm((a), (b), (c))
#define MFMA1K_ASM 1
#endif

#if __has_builtin(__builtin_amdgcn_exp2f)
#define EXP2F(x) __builtin_amdgcn_exp2f(x)
#else
#define EXP2F(x) exp2f(x)
#endif

union U8 { u16 h[8]; uint4 v; };

__device__ __forceinline__ U8 cvt8(float4 a, float4 b) {
    U8 u;
    u.h[0] = f2bf(a.x); u.h[1] = f2bf(a.y); u.h[2] = f2bf(a.z); u.h[3] = f2bf(a.w);
    u.h[4] = f2bf(b.x); u.h[5] = f2bf(b.y); u.h[6] = f2bf(b.z); u.h[7] = f2bf(b.w);
    return u;
}

// ---------------------------------------------------------------------------
// W transpose+cvt: Wt[n][k] bf16 = W[k][n] fp32.  64x64 LDS tiles.
// ---------------------------------------------------------------------------
struct TArgs { const float* src[4]; u16* dst[4]; };

__global__ __launch_bounds__(256)
void transpose_kernel(TArgs ta)
{
    __shared__ float T[64][65];
    const float* W = ta.src[blockIdx.z];
    u16* Wt = ta.dst[blockIdx.z];
    const int tid = threadIdx.x;
    const int bx = blockIdx.x, by = blockIdx.y;
    const int rr = tid >> 4, c4 = (tid & 15) * 4;
#pragma unroll
    for (int i = 0; i < 4; ++i) {
        int r = rr + i * 16;
        float4 v = *(const float4*)(W + (size_t)(by * 64 + r) * 1024 + bx * 64 + c4);
        T[r][c4] = v.x; T[r][c4 + 1] = v.y; T[r][c4 + 2] = v.z; T[r][c4 + 3] = v.w;
    }
    __syncthreads();
#pragma unroll
    for (int i = 0; i < 4; ++i) {
        int n = rr + i * 16;
        u16 o0 = f2bf(T[c4][n]), o1 = f2bf(T[c4 + 1][n]);
        u16 o2 = f2bf(T[c4 + 2][n]), o3 = f2bf(T[c4 + 3][n]);
        uint2 pk;
        pk.x = (u32)o0 | ((u32)o1 << 16);
        pk.y = (u32)o2 | ((u32)o3 << 16);
        *(uint2*)(Wt + (size_t)(bx * 64 + n) * 1024 + by * 64 + c4) = pk;
    }
}

// ---------------------------------------------------------------------------
// NT GEMM, 64x64 tile, BK=64, z-fused outputs (known-good version).
// ---------------------------------------------------------------------------
struct GArgs {
    const u16* Bt[3];
    const float* bias[3];
    void* out[3];
    int mode[3];
};

__global__ __launch_bounds__(256, 4)
void gemm_nt_kernel(const void* __restrict__ Av, int abf, GArgs ga,
                    const float* __restrict__ resid, int M, int K,
                    int bcol0, int Nout)
{
    const int z = blockIdx.z;
    const u16* Bt = ga.Bt[z];
    const float* bias = ga.bias[z];
    void* Cout = ga.out[z];
    const int mode = ga.mode[z];

    __shared__ __align__(16) u16 As[64 * 72];
    __shared__ __align__(16) u16 Bs[64 * 72];
    const int tid = threadIdx.x;
    const int bm = blockIdx.y * 64, bn = blockIdx.x * 64;
    const int wave = tid >> 6, lane = tid & 63;
    const int quad = lane >> 4, l16 = lane & 15;
    const int wm = (wave >> 1) * 32, wn = (wave & 1) * 32;
    const int ar = tid >> 2, ac = (tid & 3) * 16;

    f32x4 acc[2][2] = {};

    for (int k0 = 0; k0 < K; k0 += 64) {
        uint4 a0v, a1v;
        if (abf) {
            const u16* A16 = (const u16*)Av + (size_t)(bm + ar) * K + k0 + ac;
            a0v = *(const uint4*)A16;
            a1v = *(const uint4*)(A16 + 8);
        } else {
            const float* ap = (const float*)Av + (size_t)(bm + ar) * K + k0 + ac;
            a0v = cvt8(*(const float4*)ap, *(const float4*)(ap + 4)).v;
            a1v = cvt8(*(const float4*)(ap + 8), *(const float4*)(ap + 12)).v;
        }
        const u16* btp = Bt + (size_t)(bcol0 + bn + ar) * K + k0 + ac;
        uint4 b0v = *(const uint4*)btp;
        uint4 b1v = *(const uint4*)(btp + 8);
        __syncthreads();
        *(uint4*)(As + ar * 72 + ac) = a0v;
        *(uint4*)(As + ar * 72 + ac + 8) = a1v;
        *(uint4*)(Bs + ar * 72 + ac) = b0v;
        *(uint4*)(Bs + ar * 72 + ac + 8) = b1v;
        __syncthreads();
#pragma unroll
        for (int kh = 0; kh < 64; kh += 32) {
            bf16x8 a0 = *(const bf16x8*)(As + (wm + l16) * 72 + kh + quad * 8);
            bf16x8 a1 = *(const bf16x8*)(As + (wm + 16 + l16) * 72 + kh + quad * 8);
            bf16x8 b0 = *(const bf16x8*)(Bs + (wn + l16) * 72 + kh + quad * 8);
            bf16x8 b1 = *(const bf16x8*)(Bs + (wn + 16 + l16) * 72 + kh + quad * 8);
            acc[0][0] = MFMA16(a0, b0, acc[0][0]);
            acc[0][1] = MFMA16(a0, b1, acc[0][1]);
            acc[1][0] = MFMA16(a1, b0, acc[1][0]);
            acc[1][1] = MFMA16(a1, b1, acc[1][1]);
        }
    }

#pragma unroll
    for (int i = 0; i < 2; ++i) {
#pragma unroll
        for (int j = 0; j < 2; ++j) {
            int col = bn + wn + j * 16 + l16;
            float bb = bias[bcol0 + col];
#pragma unroll
            for (int r = 0; r < 4; ++r) {
                int row = bm + wm + i * 16 + quad * 4 + r;
                float v = acc[i][j][r] + bb;
                if (mode == 0) {
                    ((u16*)Cout)[(size_t)row * Nout + col] = f2bf(v);
                } else if (mode == 1) {
                    ((u16*)Cout)[(size_t)col * M + row] = f2bf(v);
                } else {
                    ((float*)Cout)[(size_t)row * Nout + col] = v + resid[(size_t)row * Nout + col];
                }
            }
        }
    }
}

// ---------------------------------------------------------------------------
// Far-tile constants: cst[(hg*4+w)*2048+s]
// ---------------------------------------------------------------------------
__global__ __launch_bounds__(256)
void consts_kernel(const u16* __restrict__ Qg, const u16* __restrict__ Kg,
                   const u16* __restrict__ posKg, const u16* __restrict__ posQg,
                   float* __restrict__ cst, int ld)
{
    const int s = blockIdx.x * 256 + threadIdx.x;
    const int hg = blockIdx.y;
    float d0 = 0.f, d1 = 0.f, d2 = 0.f, d3 = 0.f;
#pragma unroll
    for (int c = 0; c < 64; c += 8) {
        U8 q, k, p0, p1, r0, r1;
        q.v  = *(const uint4*)(Qg + (size_t)s * ld + hg * 64 + c);
        k.v  = *(const uint4*)(Kg + (size_t)s * ld + hg * 64 + c);
        p0.v = *(const uint4*)(posKg + (size_t)0 * ld + hg * 64 + c);
        p1.v = *(const uint4*)(posKg + (size_t)1023 * ld + hg * 64 + c);
        r0.v = *(const uint4*)(posQg + (size_t)0 * ld + hg * 64 + c);
        r1.v = *(const uint4*)(posQg + (size_t)1023 * ld + hg * 64 + c);
#pragma unroll
        for (int j = 0; j < 8; ++j) {
            float qq = bf2f(q.h[j]), kk = bf2f(k.h[j]);
            d0 += qq * bf2f(p0.h[j]);
            d1 += qq * bf2f(p1.h[j]);
            d2 += kk * bf2f(r0.h[j]);
            d3 += kk * bf2f(r1.h[j]);
        }
    }
    cst[(size_t)(hg * 4 + 0) * 2048 + s] = d0;
    cst[(size_t)(hg * 4 + 1) * 2048 + s] = d1;
    cst[(size_t)(hg * 4 + 2) * 2048 + s] = d2;
    cst[(size_t)(hg * 4 + 3) * 2048 + s] = d3;
}

// ---------------------------------------------------------------------------
// Fused flash attention.  r9 numerics (scalar RNE f2bf everywhere -- the r11
// cvt_pk packing was mis-ordered and is fully reverted) + the T14 async
// stage: next tile's 12 global loads issued as NAMED uint4 locals at the
// iteration top (no arrays -> no scratch), pinned by sched_barrier(0); LDS
// writes after B2.  The vmcnt drain then lands under ~300-600cy of
// S^T/band compute instead of being fully exposed.
// LDS = 72960 B -> 2 blocks/CU (unchanged).
// ---------------------------------------------------------------------------
__global__ __launch_bounds__(256, 2)
void attn_kernel(const u16* __restrict__ Qg, const u16* __restrict__ Kg,
                 const u16* __restrict__ Vtg, const u16* __restrict__ posKg,
                 const u16* __restrict__ posQg, const float* __restrict__ cst,
                 u16* __restrict__ ctx, int h0, int ld)
{
    __shared__ __align__(16) u16 Ks[64 * 72];
    __shared__ __align__(16) u16 Vs[64 * 72];
    __shared__ __align__(16) u16 pKs[128 * 72];
    __shared__ __align__(16) u16 pQs[128 * 72];
    __shared__ __align__(16) u16 bandC[4 * 16 * 72];
    __shared__ __align__(16) u16 bandP[16 * 264];
    const int tid = threadIdx.x;

    int hg, qi;
    if (gridDim.y == 16) {
        const int b = blockIdx.x + (blockIdx.y << 5);
        const int xcd = b & 7, r = b >> 3;
        hg = (xcd << 1) | (r & 1);
        qi = r >> 1;
    } else {
        hg = blockIdx.y; qi = blockIdx.x;
    }
    const int q0 = qi * 64;
    const int wave = tid >> 6, lane = tid & 63, quad = lane >> 4, l16 = lane & 15;
    const float CSC = 0.07216878364870322f * 1.44269504f;

    bf16x8 aq0 = *(const bf16x8*)(Qg + (q0 + wave * 16 + l16) * ld + hg * 64 + quad * 8);
    bf16x8 aq1 = *(const bf16x8*)(Qg + (q0 + wave * 16 + l16) * ld + hg * 64 + 32 + quad * 8);

    float cq0s = 0.f, cq1s = 0.f;
    if (cst) {
        int qgl = q0 + wave * 16 + l16;
        cq0s = cst[(hg * 4 + 0) * 2048 + qgl];
        cq1s = cst[(hg * 4 + 1) * 2048 + qgl];
    }

    const int sm0 = tid >> 3, sd0 = (tid & 7) * 8;
    const int sm1 = sm0 + 32;

    auto isfar = [&](int kt) {
        const int d = kt - q0;
        return cst && (d >= 576 || d <= -576);
    };

    // synchronous stage (prologue only)
    auto stage = [&](int kt, bool withpos) {
        const u16* kgb = Kg + hg * 64 + sd0;
        const u16* vgb = Vtg + kt + sd0;
        uint4 k0 = *(const uint4*)(kgb + (kt + sm0) * ld);
        uint4 k1 = *(const uint4*)(kgb + (kt + sm1) * ld);
        uint4 v0 = *(const uint4*)(vgb + (hg * 64 + sm0) * 2048);
        uint4 v1 = *(const uint4*)(vgb + (hg * 64 + sm1) * 2048);
        if (withpos) {
            const int kap = q0 - kt + 449;
            int r0 = kap + sm0;      r0 = r0 < 0 ? 0 : (r0 > 1023 ? 1023 : r0);
            int r1 = kap + sm0 + 32; r1 = r1 < 0 ? 0 : (r1 > 1023 ? 1023 : r1);
            int r2 = kap + sm0 + 64; r2 = r2 < 0 ? 0 : (r2 > 1023 ? 1023 : r2);
            int r3 = kap + sm0 + 96; r3 = r3 < 0 ? 0 : (r3 > 1023 ? 1023 : r3);
            const u16* pKb = posKg + hg * 64 + sd0;
            const u16* pQb = posQg + hg * 64 + sd0;
            uint4 a0 = *(const uint4*)(pKb + r0 * ld);
            uint4 a1 = *(const uint4*)(pKb + r1 * ld);
            uint4 a2 = *(const uint4*)(pKb + r2 * ld);
            uint4 a3 = *(const uint4*)(pKb + r3 * ld);
            uint4 b0 = *(const uint4*)(pQb + r0 * ld);
            uint4 b1 = *(const uint4*)(pQb + r1 * ld);
            uint4 b2 = *(const uint4*)(pQb + r2 * ld);
            uint4 b3 = *(const uint4*)(pQb + r3 * ld);
            *(uint4*)(Ks + sm0 * 72 + sd0) = k0;
            *(uint4*)(Ks + sm1 * 72 + sd0) = k1;
            *(uint4*)(Vs + sm0 * 72 + sd0) = v0;
            *(uint4*)(Vs + sm1 * 72 + sd0) = v1;
            *(uint4*)(pKs + sm0 * 72 + sd0) = a0;
            *(uint4*)(pKs + (sm0 + 32) * 72 + sd0) = a1;
            *(uint4*)(pKs + (sm0 + 64) * 72 + sd0) = a2;
            *(uint4*)(pKs + (sm0 + 96) * 72 + sd0) = a3;
            *(uint4*)(pQs + sm0 * 72 + sd0) = b0;
            *(uint4*)(pQs + (sm0 + 32) * 72 + sd0) = b1;
            *(uint4*)(pQs + (sm0 + 64) * 72 + sd0) = b2;
            *(uint4*)(pQs + (sm0 + 96) * 72 + sd0) = b3;
        } else {
            *(uint4*)(Ks + sm0 * 72 + sd0) = k0;
            *(uint4*)(Ks + sm1 * 72 + sd0) = k1;
            *(uint4*)(Vs + sm0 * 72 + sd0) = v0;
            *(uint4*)(Vs + sm1 * 72 + sd0) = v1;
        }
    };

    auto bandcomp = [&]() {
        bf16x8 aP0 = *(const bf16x8*)(Ks + (wave * 16 + l16) * 72 + quad * 8);
        bf16x8 aP1 = *(const bf16x8*)(Ks + (wave * 16 + l16) * 72 + 32 + quad * 8);
        const int iC0 = wave * 16 + l16;
        const int iP0 = 48 - wave * 16 + l16;
        u16* bC = bandC + wave * 1152;
        u16* bP = bandP;
#pragma unroll
        for (int n = 0; n < 5; ++n) {
            const u16* pK = pKs + (iC0 + n * 16) * 72;
            const u16* pQ = pQs + (iP0 + n * 16) * 72;
            bf16x8 bK0 = *(const bf16x8*)(pK + quad * 8);
            bf16x8 bK1 = *(const bf16x8*)(pK + 32 + quad * 8);
            bf16x8 bQ0 = *(const bf16x8*)(pQ + quad * 8);
            bf16x8 bQ1 = *(const bf16x8*)(pQ + 32 + quad * 8);
            f32x4 aC = {0.f, 0.f, 0.f, 0.f}, aP = {0.f, 0.f, 0.f, 0.f};
            aC = MFMA16(aq0, bK0, aC);
            aC = MFMA16(aq1, bK1, aC);
            aP = MFMA16(aP0, bQ0, aP);
            aP = MFMA16(aP1, bQ1, aP);
#pragma unroll
            for (int r = 0; r < 4; ++r) {
                int q15 = quad * 4 + r;
                int k = q15 + 63 - n * 16 - l16;
                if ((unsigned)k < 64u) bC[q15 * 72 + k] = f2bf(aC[r]);
                int qs = n * 16 + l16 + quad * 4 + r - 15;
                if ((unsigned)qs < 64u) bP[(wave * 4 + quad) * 264 + qs * 4 + r] = f2bf(aP[r]);
            }
        }
    };

    stage(0, !isfar(0));
    __syncthreads();

    f32x4 OTa[4] = {}, OTb[4] = {};
    float lr4[4] = {0.f, 0.f, 0.f, 0.f};

    for (int kt = 0; kt < 2048; kt += 64) {
        const int diff = kt - q0;
        const bool far = cst && (diff >= 576 || diff <= -576);
        const bool havenext = (kt + 64 < 2048);
        const bool nextnear = havenext && !isfar(kt + 64);

        // ---- T14: early-issue next tile's global loads into NAMED registers
        uint4 nk0, nk1, nv0, nv1, na0, na1, na2, na3, nb0, nb1, nb2, nb3;
        if (havenext) {
            const int ktn = kt + 64;
            const u16* kgb = Kg + hg * 64 + sd0;
            const u16* vgb = Vtg + ktn + sd0;
            nk0 = *(const uint4*)(kgb + (ktn + sm0) * ld);
            nk1 = *(const uint4*)(kgb + (ktn + sm1) * ld);
            nv0 = *(const uint4*)(vgb + (hg * 64 + sm0) * 2048);
            nv1 = *(const uint4*)(vgb + (hg * 64 + sm1) * 2048);
            if (nextnear) {
                const int kap = q0 - ktn + 449;
                int r0 = kap + sm0;      r0 = r0 < 0 ? 0 : (r0 > 1023 ? 1023 : r0);
                int r1 = kap + sm0 + 32; r1 = r1 < 0 ? 0 : (r1 > 1023 ? 1023 : r1);
                int r2 = kap + sm0 + 64; r2 = r2 < 0 ? 0 : (r2 > 1023 ? 1023 : r2);
                int r3 = kap + sm0 + 96; r3 = r3 < 0 ? 0 : (r3 > 1023 ? 1023 : r3);
                const u16* pKb = posKg + hg * 64 + sd0;
                const u16* pQb = posQg + hg * 64 + sd0;
                na0 = *(const uint4*)(pKb + r0 * ld);
                na1 = *(const uint4*)(pKb + r1 * ld);
                na2 = *(const uint4*)(pKb + r2 * ld);
                na3 = *(const uint4*)(pKb + r3 * ld);
                nb0 = *(const uint4*)(pQb + r0 * ld);
                nb1 = *(const uint4*)(pQb + r1 * ld);
                nb2 = *(const uint4*)(pQb + r2 * ld);
                nb3 = *(const uint4*)(pQb + r3 * ld);
            }
        }
#if __has_builtin(__builtin_amdgcn_sched_barrier)
        __builtin_amdgcn_sched_barrier(0);   // pin loads above compute
#endif

        // ---- S^T = K Q^T : lane reg r of tile j: k = j*16+quad*4+r, q = l16
        f32x4 sT[4];
#pragma unroll
        for (int j = 0; j < 4; ++j) {
            f32x4 z = {0.f, 0.f, 0.f, 0.f};
            bf16x8 a0 = *(const bf16x8*)(Ks + (j * 16 + l16) * 72 + quad * 8);
            bf16x8 a1 = *(const bf16x8*)(Ks + (j * 16 + l16) * 72 + 32 + quad * 8);
            z = MFMA16(a0, aq0, z);
            z = MFMA16(a1, aq1, z);
            sT[j] = z;
        }

        if (!far) {
            bandcomp();
            __syncthreads();   // B1: band writes visible (drains loads under cover)
        }

        // ---- logits + exp -> P^T fragments in registers (scalar RNE f2bf)
        bf16x4 pb[4];
        if (far) {
            const float cqs = (diff > 0) ? cq0s : cq1s;
            const float* pc = cst + (hg * 4 + (diff > 0 ? 2 : 3)) * 2048 + kt;
#pragma unroll
            for (int j = 0; j < 4; ++j) {
                float4 ck4 = *(const float4*)(pc + j * 16 + quad * 4);
                const float* ck = (const float*)&ck4;
#pragma unroll
                for (int r = 0; r < 4; ++r) {
                    float t = sT[j][r] + cqs + ck[r];
                    float e = EXP2F(fminf(t * CSC, 86.5f));
                    lr4[j] += e;
                    pb[j][r] = (short)f2bf(e);
                }
            }
        } else {
            const u16* bC = bandC + wave * 1152 + l16 * 72;
            const u16* bP = bandP + (wave * 16 + l16) * 4;
#pragma unroll
            for (int j = 0; j < 4; ++j) {
                u16x4 c4 = *(const u16x4*)(bC + j * 16 + quad * 4);
                u16x4 p4 = *(const u16x4*)(bP + (j * 4 + quad) * 264);
#pragma unroll
                for (int r = 0; r < 4; ++r) {
                    float t = sT[j][r] + bf2f(c4[r]) + bf2f(p4[r]);
                    float e = EXP2F(fminf(t * CSC, 86.5f));
                    lr4[j] += e;
                    pb[j][r] = (short)f2bf(e);
                }
            }
        }

        // ---- PV: O^T += Vt * P^T  (dual accumulators)
#pragma unroll
        for (int jd = 0; jd < 4; ++jd) {
            const u16* vrow = Vs + (jd * 16 + l16) * 72;
            OTa[jd] = MFMA1K(*(const bf16x4*)(vrow + quad * 4), pb[0], OTa[jd]);
            OTb[jd] = MFMA1K(*(const bf16x4*)(vrow + 16 + quad * 4), pb[1], OTb[jd]);
            OTa[jd] = MFMA1K(*(const bf16x4*)(vrow + 32 + quad * 4), pb[2], OTa[jd]);
            OTb[jd] = MFMA1K(*(const bf16x4*)(vrow + 48 + quad * 4), pb[3], OTb[jd]);
        }

        __syncthreads();       // B2: all tile-t LDS reads done
        if (havenext) {
            // ---- write the held registers (loads long since landed)
            *(uint4*)(Ks + sm0 * 72 + sd0) = nk0;
            *(uint4*)(Ks + sm1 * 72 + sd0) = nk1;
            *(uint4*)(Vs + sm0 * 72 + sd0) = nv0;
            *(uint4*)(Vs + sm1 * 72 + sd0) = nv1;
            if (nextnear) {
                *(uint4*)(pKs + sm0 * 72 + sd0) = na0;
                *(uint4*)(pKs + (sm0 + 32) * 72 + sd0) = na1;
                *(uint4*)(pKs + (sm0 + 64) * 72 + sd0) = na2;
                *(uint4*)(pKs + (sm0 + 96) * 72 + sd0) = na3;
                *(uint4*)(pQs + sm0 * 72 + sd0) = nb0;
                *(uint4*)(pQs + (sm0 + 32) * 72 + sd0) = nb1;
                *(uint4*)(pQs + (sm0 + 64) * 72 + sd0) = nb2;
                *(uint4*)(pQs + (sm0 + 96) * 72 + sd0) = nb3;
            }
            __syncthreads();   // B3: next-tile LDS visible
        }
    }

#if MFMA1K_ASM
    asm volatile("s_nop 7\n\ts_nop 7" ::);
#endif

    float lr = (lr4[0] + lr4[1]) + (lr4[2] + lr4[3]);
    lr += __shfl_xor(lr, 16, 64);
    lr += __shfl_xor(lr, 32, 64);
    float inv = 1.0f / fmaxf(lr, 1e-20f);
    const int row = q0 + wave * 16 + l16;
#pragma unroll
    for (int jd = 0; jd < 4; ++jd) {
        u16x4 o;
#pragma unroll
        for (int r = 0; r < 4; ++r) o[r] = f2bf((OTa[jd][r] + OTb[jd][r]) * inv);
        *(u16x4*)(ctx + row * 1024 + (h0 + hg) * 64 + jd * 16 + quad * 4) = o;
    }
}

// ---------------------------------------------------------------------------
// Row LayerNorm: x (fp32, ws) -> d_out (fp32)
// ---------------------------------------------------------------------------
__global__ __launch_bounds__(256, 4)
void ln_kernel(const float* __restrict__ x, const float* __restrict__ g,
               const float* __restrict__ b, float* __restrict__ out)
{
    const int row = blockIdx.x;
    const int tid = threadIdx.x;
    const int wave = tid >> 6, lane = tid & 63;
    const float* xr = x + (size_t)row * 1024;
    float v[4]; float s = 0.f;
#pragma unroll
    for (int i = 0; i < 4; ++i) { v[i] = xr[tid + i * 256]; s += v[i]; }
    __shared__ float red[4];
    __shared__ float red2[4];
#pragma unroll
    for (int m = 1; m < 64; m <<= 1) s += __shfl_xor(s, m, 64);
    if (lane == 0) red[wave] = s;
    __syncthreads();
    float mu = (red[0] + red[1] + red[2] + red[3]) * (1.f / 1024.f);
    float vs = 0.f;
#pragma unroll
    for (int i = 0; i < 4; ++i) { float d = v[i] - mu; vs += d * d; }
#pragma unroll
    for (int m = 1; m < 64; m <<= 1) vs += __shfl_xor(vs, m, 64);
    if (lane == 0) red2[wave] = vs;
    __syncthreads();
    float var = (red2[0] + red2[1] + red2[2] + red2[3]) * (1.f / 1024.f);
    float rstd = rsqrtf(var + 1e-5f);
#pragma unroll
    for (int i = 0; i < 4; ++i) {
        int c = tid + i * 256;
        out[(size_t)row * 1024 + c] = (v[i] - mu) * rstd * g[c] + b[c];
    }
}

// ---------------------------------------------------------------------------
extern "C" void kernel_launch(void* const* d_in, const int* in_sizes, int n_in,
                              void* d_out, int out_size, void* d_ws, size_t ws_size,
                              hipStream_t stream)
{
    const float* hs  = (const float*)d_in[0];
    const float* rel = (const float*)d_in[2];
    const float* Wq  = (const float*)d_in[3];
    const float* bq  = (const float*)d_in[4];
    const float* Wk  = (const float*)d_in[5];
    const float* bk  = (const float*)d_in[6];
    const float* Wv  = (const float*)d_in[7];
    const float* bv  = (const float*)d_in[8];
    const float* Wo  = (const float*)d_in[9];
    const float* bo  = (const float*)d_in[10];
    const float* lng = (const float*)d_in[11];
    const float* lnb = (const float*)d_in[12];

    u16* Wqt = (u16*)d_out;
    u16* Wkt = Wqt + (size_t)1024 * 1024;
    u16* Wvt = Wkt + (size_t)1024 * 1024;
    u16* Wot = Wvt + (size_t)1024 * 1024;
    float* cst = (float*)d_out;          // 16*4*2048 floats = 512 KB

    const size_t MB = 1024 * 1024;
    size_t fixed = 256 + 4 * MB + 4096;
    int G = 1;
    if (ws_size > fixed + MB) {
        size_t g = (ws_size - fixed) / MB;
        G = g > 16 ? 16 : (int)g;
    }
    if (G < 1) G = 1;

    char* w = (char*)d_ws;
    size_t off = 0;
    auto take = [&](size_t n) { void* p = w + off; off = (off + n + 255) & ~(size_t)255; return p; };
    (void)take(256);
    u16* ctx = (u16*)take((size_t)2048 * 1024 * 2);
    float* xalt = nullptr;
    if (G < 8) {
        size_t budget = (ws_size > fixed + 8 * MB) ? (ws_size - fixed - 8 * MB) / MB : 1;
        G = budget < 1 ? 1 : (budget > 16 ? 16 : (int)budget);
        xalt = (float*)take((size_t)2048 * 1024 * 4);
    }
    u16* Qg    = (u16*)take((size_t)2048 * 64 * G * 2);
    u16* Kg    = (u16*)take((size_t)2048 * 64 * G * 2);
    u16* Vtg   = (u16*)take((size_t)64 * G * 2048 * 2);
    u16* posKg = (u16*)take((size_t)1024 * 64 * G * 2);
    u16* posQg = (u16*)take((size_t)1024 * 64 * G * 2);
    float* x = xalt ? xalt : (float*)Qg;

    dim3 blk(256);

    TArgs ta;
    ta.src[0] = Wq; ta.src[1] = Wk; ta.src[2] = Wv; ta.src[3] = Wo;
    ta.dst[0] = Wqt; ta.dst[1] = Wkt; ta.dst[2] = Wvt; ta.dst[3] = Wot;
    transpose_kernel<<<dim3(16, 16, 4), blk, 0, stream>>>(ta);

    const bool full = (G == 16);
    for (int h0 = 0; h0 < 16; h0 += G) {
        int gcnt = (16 - h0) < G ? (16 - h0) : G;
        int Ng = 64 * gcnt, bc0 = 64 * h0;

        GArgs qa;
        qa.Bt[0] = Wqt; qa.bias[0] = bq; qa.out[0] = Qg;  qa.mode[0] = 0;
        qa.Bt[1] = Wkt; qa.bias[1] = bk; qa.out[1] = Kg;  qa.mode[1] = 0;
        qa.Bt[2] = Wvt; qa.bias[2] = bv; qa.out[2] = Vtg; qa.mode[2] = 1;
        gemm_nt_kernel<<<dim3(gcnt, 32, 3), blk, 0, stream>>>(hs, 0, qa, nullptr, 2048, 1024, bc0, Ng);

        GArgs pa;
        pa.Bt[0] = Wkt; pa.bias[0] = bk; pa.out[0] = posKg; pa.mode[0] = 0;
        pa.Bt[1] = Wqt; pa.bias[1] = bq; pa.out[1] = posQg; pa.mode[1] = 0;
        pa.Bt[2] = Wqt; pa.bias[2] = bq; pa.out[2] = posQg; pa.mode[2] = 0;  // unused z
        gemm_nt_kernel<<<dim3(gcnt, 16, 2), blk, 0, stream>>>(rel, 0, pa, nullptr, 1024, 1024, bc0, Ng);

        if (full)
            consts_kernel<<<dim3(8, G), blk, 0, stream>>>(Qg, Kg, posKg, posQg, cst, Ng);

        attn_kernel<<<dim3(32, gcnt), blk, 0, stream>>>(Qg, Kg, Vtg, posKg, posQg,
                                                        full ? cst : nullptr, ctx, h0, Ng);
    }

    GArgs fa;
    fa.Bt[0] = Wot; fa.bias[0] = bo; fa.out[0] = x; fa.mode[0] = 2;
    fa.Bt[1] = Wot; fa.bias[1] = bo; fa.out[1] = x; fa.mode[1] = 2;  // unused z
    fa.Bt[2] = Wot; fa.bias[2] = bo; fa.out[2] = x; fa.mode[2] = 2;  // unused z
    gemm_nt_kernel<<<dim3(16, 32, 1), blk, 0, stream>>>(ctx, 1, fa, hs, 2048, 1024, 0, 1024);

    ln_kernel<<<dim3(2048), blk, 0, stream>>>(x, lng, lnb, (float*)d_out);
}